// Round 1
// baseline (182.766 us; speedup 1.0000x reference)
//
#include <hip/hip_runtime.h>
#include <hip/hip_bf16.h>

namespace {
constexpr int kH = 192, kW = 640, kHW = kH * kW;
constexpr int kB = 2, kC = 64;          // batch, image channels
constexpr int kN0 = 40000, kC0 = 32;    // level0 points/channels
constexpr int kN1 = 20000, kC1 = 64;    // level1 points/channels
constexpr int kCL = 67;                 // C1 + 3

// ---------------------------------------------------------------------------
// winner-index scatter (last-write-wins == max point index wins)
// ---------------------------------------------------------------------------
__global__ void init_winners(int* __restrict__ w, int n) {
  int i = blockIdx.x * blockDim.x + threadIdx.x;
  if (i < n) w[i] = -1;
}

__global__ void scatter_win(const float* __restrict__ coor, int N,
                            int* __restrict__ win) {
  int idx = blockIdx.x * blockDim.x + threadIdx.x;
  if (idx >= kB * N) return;
  int b = idx / N;
  float u = coor[(size_t)idx * 2 + 0];
  float v = coor[(size_t)idx * 2 + 1];
  u = fminf(fmaxf(u, 0.f), 1.f);
  v = fminf(fmaxf(v, 0.f), 1.f);
  // rc[:,0] = coor[:,1]*H (row), rc[:,1] = coor[:,0]*W (col), truncate
  int r = (int)(v * (float)kH);
  int c = (int)(u * (float)kW);
  if (r < kH && c < kW) {
    int n = idx - b * N;
    atomicMax(&win[b * kHW + r * kW + c], n);
  }
}

// ---------------------------------------------------------------------------
// fused: gather p0/p1 -> t = W0@p0 + b0 + p1 -> e = W2@t + b2
//        g = W3 . x_rgb + b3 ; fused = g + e   (written [B,67,H,W])
// Per-thread pixel. Accumulators fully unrolled (compile-time indices);
// reduction operand goes through a private LDS column (stride 256, no
// conflicts, no barriers). Weight reads are wave-uniform -> s_load.
// ---------------------------------------------------------------------------
__global__ __launch_bounds__(256) void kfused(
    const float* __restrict__ x_rgb,
    const float* __restrict__ feat0, const float* __restrict__ vox0,
    const float* __restrict__ feat1, const float* __restrict__ vox1,
    const int* __restrict__ win0, const int* __restrict__ win1,
    const float* __restrict__ W0, const float* __restrict__ b0,
    const float* __restrict__ W2, const float* __restrict__ b2,
    const float* __restrict__ W3, const float* __restrict__ b3,
    float* __restrict__ fusedbuf) {
  __shared__ float Ts[kCL * 256];  // 68.6 KB -> 2 blocks/CU
  const int tid = threadIdx.x;
  const int pix = blockIdx.x * 256 + tid;  // grid sized exactly B*HW/256
  const int b = pix / kHW;
  const int p = pix - b * kHW;

  const int w0 = win0[pix];
  const int w1 = win1[pix];

  // stage p0 (35) into private LDS column
  if (w0 >= 0) {
    const float* f0 = feat0 + ((size_t)b * kN0 + w0) * kC0;
#pragma unroll
    for (int i = 0; i < kC0; ++i) Ts[i * 256 + tid] = f0[i];
    const float* v0 = vox0 + ((size_t)b * kN0 + w0) * 3;
    Ts[(kC0 + 0) * 256 + tid] = v0[0];
    Ts[(kC0 + 1) * 256 + tid] = v0[1];
    Ts[(kC0 + 2) * 256 + tid] = v0[2];
  } else {
#pragma unroll
    for (int i = 0; i < kC0 + 3; ++i) Ts[i * 256 + tid] = 0.f;
  }

  // t = b0 + p1
  float t[kCL];
  if (w1 >= 0) {
    const float* f1 = feat1 + ((size_t)b * kN1 + w1) * kC1;
#pragma unroll
    for (int co = 0; co < kC1; ++co) t[co] = b0[co] + f1[co];
    const float* v1 = vox1 + ((size_t)b * kN1 + w1) * 3;
    t[kC1 + 0] = b0[kC1 + 0] + v1[0];
    t[kC1 + 1] = b0[kC1 + 1] + v1[1];
    t[kC1 + 2] = b0[kC1 + 2] + v1[2];
  } else {
#pragma unroll
    for (int co = 0; co < kCL; ++co) t[co] = b0[co];
  }

  // t += W0 @ p0   (ci runtime/uniform, co unrolled)
  for (int ci = 0; ci < kC0 + 3; ++ci) {
    float tv = Ts[ci * 256 + tid];
#pragma unroll
    for (int co = 0; co < kCL; ++co) t[co] += W0[co * (kC0 + 3) + ci] * tv;
  }

  // round-trip t through LDS so matvec2 can read it with a runtime index
#pragma unroll
  for (int co = 0; co < kCL; ++co) Ts[co * 256 + tid] = t[co];

  float e[kCL];
#pragma unroll
  for (int co = 0; co < kCL; ++co) e[co] = b2[co];
  for (int ci = 0; ci < kCL; ++ci) {
    float tv = Ts[ci * 256 + tid];
#pragma unroll
    for (int co = 0; co < kCL; ++co) e[co] += W2[co * kCL + ci] * tv;
  }

  // gate scalar
  float g = b3[0];
  const float* xr = x_rgb + (size_t)b * kC * kHW + p;
  for (int c = 0; c < kC; ++c) g += W3[c] * xr[(size_t)c * kHW];

  float* fp = fusedbuf + (size_t)b * kCL * kHW + p;
#pragma unroll
  for (int co = 0; co < kCL; ++co) fp[(size_t)co * kHW] = g + e[co];
}

// ---------------------------------------------------------------------------
// att = sigmoid(conv3x3(fused)) ; out = x_rgb * att
// ---------------------------------------------------------------------------
__global__ __launch_bounds__(256) void katt(
    const float* __restrict__ x_rgb, const float* __restrict__ fusedbuf,
    const float* __restrict__ Wsp, const float* __restrict__ bsp,
    float* __restrict__ out) {
  const int pix = blockIdx.x * 256 + threadIdx.x;
  const int b = pix / kHW;
  const int p = pix - b * kHW;
  const int h = p / kW;
  const int w = p - h * kW;

  const bool vu = h > 0, vd = h < kH - 1, vl = w > 0, vr = w < kW - 1;
  float acc = bsp[0];
  const float* fb = fusedbuf + (size_t)b * kCL * kHW + p;
  for (int c = 0; c < kCL; ++c) {
    const float* fc = fb + (size_t)c * kHW;
    const float* wk = Wsp + c * 9;
    float s00 = (vu && vl) ? fc[-kW - 1] : 0.f;
    float s01 = vu ? fc[-kW] : 0.f;
    float s02 = (vu && vr) ? fc[-kW + 1] : 0.f;
    float s10 = vl ? fc[-1] : 0.f;
    float s11 = fc[0];
    float s12 = vr ? fc[1] : 0.f;
    float s20 = (vd && vl) ? fc[kW - 1] : 0.f;
    float s21 = vd ? fc[kW] : 0.f;
    float s22 = (vd && vr) ? fc[kW + 1] : 0.f;
    acc += wk[0] * s00 + wk[1] * s01 + wk[2] * s02 + wk[3] * s10 +
           wk[4] * s11 + wk[5] * s12 + wk[6] * s20 + wk[7] * s21 +
           wk[8] * s22;
  }
  float att = 1.f / (1.f + __expf(-acc));
  const float* xr = x_rgb + (size_t)b * kC * kHW + p;
  float* op = out + (size_t)b * kC * kHW + p;
  for (int c = 0; c < kC; ++c) op[(size_t)c * kHW] = xr[(size_t)c * kHW] * att;
}

}  // namespace

extern "C" void kernel_launch(void* const* d_in, const int* in_sizes, int n_in,
                              void* d_out, int out_size, void* d_ws,
                              size_t ws_size, hipStream_t stream) {
  const float* x_rgb = (const float*)d_in[0];
  const float* feat0 = (const float*)d_in[1];
  const float* coor0 = (const float*)d_in[2];
  const float* vox0 = (const float*)d_in[3];
  const float* feat1 = (const float*)d_in[4];
  const float* coor1 = (const float*)d_in[5];
  const float* vox1 = (const float*)d_in[6];
  const float* W0 = (const float*)d_in[7];
  const float* b0 = (const float*)d_in[8];
  const float* W2 = (const float*)d_in[9];
  const float* b2 = (const float*)d_in[10];
  const float* W3 = (const float*)d_in[11];
  const float* b3 = (const float*)d_in[12];
  const float* Wsp = (const float*)d_in[13];
  const float* bsp = (const float*)d_in[14];
  float* out = (float*)d_out;

  // workspace layout: fused [B,67,H,W] f32 | winner0 [B*HW] i32 | winner1
  const size_t fused_elems = (size_t)kB * kCL * kHW;  // 16,465,920 (65.9 MB)
  float* fusedbuf = (float*)d_ws;
  int* win0 = (int*)((char*)d_ws + fused_elems * sizeof(float));
  int* win1 = win0 + kB * kHW;

  const int nwin = 2 * kB * kHW;
  init_winners<<<(nwin + 255) / 256, 256, 0, stream>>>(win0, nwin);
  scatter_win<<<(kB * kN0 + 255) / 256, 256, 0, stream>>>(coor0, kN0, win0);
  scatter_win<<<(kB * kN1 + 255) / 256, 256, 0, stream>>>(coor1, kN1, win1);
  kfused<<<kB * kHW / 256, 256, 0, stream>>>(x_rgb, feat0, vox0, feat1, vox1,
                                             win0, win1, W0, b0, W2, b2, W3,
                                             b3, fusedbuf);
  katt<<<kB * kHW / 256, 256, 0, stream>>>(x_rgb, fusedbuf, Wsp, bsp, out);
}

// Round 2
// 90.374 us; speedup vs baseline: 2.0223x; 2.0223x over previous
//
#include <hip/hip_runtime.h>
#include <hip/hip_bf16.h>

namespace {
constexpr int kH = 192, kW = 640, kHW = kH * kW;
constexpr int kB = 2, kC = 64;          // batch, image channels
constexpr int kN0 = 40000, kC0 = 32;    // level0 points/channels
constexpr int kN1 = 20000, kC1 = 64;    // level1 points/channels
constexpr int kCL = 67;                 // C1 + 3

// ---------------------------------------------------------------------------
// winner-index scatter (last-write-wins == max point index wins)
// ---------------------------------------------------------------------------
__global__ void init_winners(int* __restrict__ w, int n) {
  int i = blockIdx.x * blockDim.x + threadIdx.x;
  if (i < n) w[i] = -1;
}

__global__ void scatter_win(const float* __restrict__ coor, int N,
                            int* __restrict__ win) {
  int idx = blockIdx.x * blockDim.x + threadIdx.x;
  if (idx >= kB * N) return;
  int b = idx / N;
  float u = coor[(size_t)idx * 2 + 0];
  float v = coor[(size_t)idx * 2 + 1];
  u = fminf(fmaxf(u, 0.f), 1.f);
  v = fminf(fmaxf(v, 0.f), 1.f);
  int r = (int)(v * (float)kH);   // row from coor[:,1]
  int c = (int)(u * (float)kW);   // col from coor[:,0]
  if (r < kH && c < kW) {
    int n = idx - b * N;
    atomicMax(&win[b * kHW + r * kW + c], n);
  }
}

// ---------------------------------------------------------------------------
// fold all linear stages into the point features (single block):
//   b'   = W2 @ b0 + b2                      [67]
//   A1   = Wsp^T @ W2                        [9,67]  (tap-projected level-1 matrix)
//   M0   = A1 @ W0                           [9,35]  (tap-projected level-0 matrix)
//   sb_k = sum_c Wsp[c,k] * b'[c]            [9]
//   ws_k = sum_c Wsp[c,k]                    [9]     (gate projection per tap)
// ---------------------------------------------------------------------------
__global__ __launch_bounds__(640) void kprecomp(
    const float* __restrict__ W0, const float* __restrict__ b0,
    const float* __restrict__ W2, const float* __restrict__ b2,
    const float* __restrict__ Wsp,
    float* __restrict__ M0, float* __restrict__ A1g,
    float* __restrict__ sb, float* __restrict__ wsum) {
  __shared__ float A1s[9 * kCL];
  __shared__ float bp[kCL];
  const int t = threadIdx.x;
  if (t < kCL) {  // b' = W2@b0 + b2
    float s = b2[t];
    for (int j = 0; j < kCL; ++j) s += W2[t * kCL + j] * b0[j];
    bp[t] = s;
  }
  if (t < 9 * kCL) {  // A1[k][j] = sum_c Wsp[c*9+k] * W2[c*67+j]
    int k = t / kCL, j = t - k * kCL;
    float s = 0.f;
    for (int c = 0; c < kCL; ++c) s += Wsp[c * 9 + k] * W2[c * kCL + j];
    A1s[t] = s;
    A1g[t] = s;
  }
  __syncthreads();
  if (t < 9 * 35) {  // M0[k][i] = sum_j A1[k][j] * W0[j*35+i]
    int k = t / 35, i = t - k * 35;
    float s = 0.f;
    for (int j = 0; j < kCL; ++j) s += A1s[k * kCL + j] * W0[j * 35 + i];
    M0[t] = s;
  }
  if (t >= 576 && t < 585) {  // sb
    int k = t - 576;
    float s = 0.f;
    for (int c = 0; c < kCL; ++c) s += Wsp[c * 9 + k] * bp[c];
    sb[k] = s;
  }
  if (t >= 592 && t < 601) {  // wsum
    int k = t - 592;
    float s = 0.f;
    for (int c = 0; c < kCL; ++c) s += Wsp[c * 9 + k];
    wsum[k] = s;
  }
}

// ---------------------------------------------------------------------------
// gate field: g[b,p] = b3 + W3 . x_rgb[b,:,p]
// ---------------------------------------------------------------------------
__global__ __launch_bounds__(256) void kgate(const float* __restrict__ x_rgb,
                                             const float* __restrict__ W3,
                                             const float* __restrict__ b3,
                                             float* __restrict__ g) {
  const int pix = blockIdx.x * 256 + threadIdx.x;
  const int b = pix / kHW;
  const int p = pix - b * kHW;
  const float* xr = x_rgb + (size_t)b * kC * kHW + p;
  float s = b3[0];
#pragma unroll
  for (int c = 0; c < kC; ++c) s += W3[c] * xr[(size_t)c * kHW];
  g[pix] = s;
}

// ---------------------------------------------------------------------------
// main: logit[p] = bsp + sum_{valid taps k} ( wsum[k]*g[q] + sb[k]
//                  + [win0[q]>=0] M0[k].p0(q) + [win1[q]>=0] A1[k].p1(q) )
//       out[c,p] = x_rgb[c,p] * sigmoid(logit[p])
// ---------------------------------------------------------------------------
__global__ __launch_bounds__(256) void kmain(
    const float* __restrict__ x_rgb, const float* __restrict__ g,
    const int* __restrict__ win0, const int* __restrict__ win1,
    const float* __restrict__ feat0, const float* __restrict__ vox0,
    const float* __restrict__ feat1, const float* __restrict__ vox1,
    const float* __restrict__ M0, const float* __restrict__ A1,
    const float* __restrict__ sb, const float* __restrict__ wsum,
    const float* __restrict__ bsp, float* __restrict__ out) {
  const int pix = blockIdx.x * 256 + threadIdx.x;
  const int b = pix / kHW;
  const int p = pix - b * kHW;
  const int h = p / kW;
  const int w = p - h * kW;

  float logit = bsp[0];
#pragma unroll
  for (int dh = -1; dh <= 1; ++dh) {
    const int hh = h + dh;
    if (hh < 0 || hh >= kH) continue;
#pragma unroll
    for (int dw = -1; dw <= 1; ++dw) {
      const int ww = w + dw;
      if (ww < 0 || ww >= kW) continue;
      const int k = (dh + 1) * 3 + (dw + 1);
      const int q = b * kHW + hh * kW + ww;
      logit += wsum[k] * g[q] + sb[k];
      const int w0 = win0[q];
      if (w0 >= 0) {
        const float* f0 = feat0 + ((size_t)b * kN0 + w0) * kC0;
        const float* m = M0 + k * 35;
        float s = 0.f;
#pragma unroll
        for (int i = 0; i < kC0; ++i) s += m[i] * f0[i];
        const float* v0 = vox0 + ((size_t)b * kN0 + w0) * 3;
        s += m[32] * v0[0] + m[33] * v0[1] + m[34] * v0[2];
        logit += s;
      }
      const int w1 = win1[q];
      if (w1 >= 0) {
        const float* f1 = feat1 + ((size_t)b * kN1 + w1) * kC1;
        const float* m = A1 + k * kCL;
        float s = 0.f;
#pragma unroll
        for (int i = 0; i < kC1; ++i) s += m[i] * f1[i];
        const float* v1 = vox1 + ((size_t)b * kN1 + w1) * 3;
        s += m[64] * v1[0] + m[65] * v1[1] + m[66] * v1[2];
        logit += s;
      }
    }
  }
  const float att = 1.f / (1.f + __expf(-logit));
  const float* xr = x_rgb + (size_t)b * kC * kHW + p;
  float* op = out + (size_t)b * kC * kHW + p;
#pragma unroll
  for (int c = 0; c < kC; ++c) op[(size_t)c * kHW] = xr[(size_t)c * kHW] * att;
}

}  // namespace

extern "C" void kernel_launch(void* const* d_in, const int* in_sizes, int n_in,
                              void* d_out, int out_size, void* d_ws,
                              size_t ws_size, hipStream_t stream) {
  const float* x_rgb = (const float*)d_in[0];
  const float* feat0 = (const float*)d_in[1];
  const float* coor0 = (const float*)d_in[2];
  const float* vox0 = (const float*)d_in[3];
  const float* feat1 = (const float*)d_in[4];
  const float* coor1 = (const float*)d_in[5];
  const float* vox1 = (const float*)d_in[6];
  const float* W0 = (const float*)d_in[7];
  const float* b0 = (const float*)d_in[8];
  const float* W2 = (const float*)d_in[9];
  const float* b2 = (const float*)d_in[10];
  const float* W3 = (const float*)d_in[11];
  const float* b3 = (const float*)d_in[12];
  const float* Wsp = (const float*)d_in[13];
  const float* bsp = (const float*)d_in[14];
  float* out = (float*)d_out;

  // workspace layout (floats / ints, all 4B aligned):
  //   g[B*HW] | win0[B*HW] | win1[B*HW] | M0[9*35] | A1[9*67] | sb[9] | wsum[9]
  float* g = (float*)d_ws;
  int* win0 = (int*)(g + (size_t)kB * kHW);
  int* win1 = win0 + (size_t)kB * kHW;
  float* M0 = (float*)(win1 + (size_t)kB * kHW);
  float* A1 = M0 + 9 * 35;
  float* sb = A1 + 9 * kCL;
  float* wsum = sb + 9;

  const int nwin = 2 * kB * kHW;
  init_winners<<<(nwin + 255) / 256, 256, 0, stream>>>(win0, nwin);
  scatter_win<<<(kB * kN0 + 255) / 256, 256, 0, stream>>>(coor0, kN0, win0);
  scatter_win<<<(kB * kN1 + 255) / 256, 256, 0, stream>>>(coor1, kN1, win1);
  kprecomp<<<1, 640, 0, stream>>>(W0, b0, W2, b2, Wsp, M0, A1, sb, wsum);
  kgate<<<kB * kHW / 256, 256, 0, stream>>>(x_rgb, W3, b3, g);
  kmain<<<kB * kHW / 256, 256, 0, stream>>>(x_rgb, g, win0, win1, feat0, vox0,
                                            feat1, vox1, M0, A1, sb, wsum, bsp,
                                            out);
}